// Round 1
// baseline (106.940 us; speedup 1.0000x reference)
//
#include <hip/hip_runtime.h>

#define V_DIM 128000
#define K_TOP 50
#define NBINS 2048
#define CAP 4096
#define BLOCK 1024
#define NWAVES (BLOCK / 64)

__device__ __forceinline__ unsigned key_of(float x) {
    unsigned b = __float_as_uint(x);
    return (b & 0x80000000u) ? ~b : (b | 0x80000000u);
}
__device__ __forceinline__ float val_of(unsigned u) {
    unsigned b = (u & 0x80000000u) ? (u ^ 0x80000000u) : ~u;
    return __uint_as_float(b);
}

__global__ __launch_bounds__(BLOCK, 1)
void topk_mask_softmax(const float* __restrict__ scores, float* __restrict__ out) {
    __shared__ unsigned hist[NBINS];
    __shared__ float    hsum[NBINS];
    __shared__ unsigned chunk[BLOCK];
    __shared__ unsigned super_[64];
    __shared__ unsigned cand_u[CAP];
    __shared__ int      cand_i[CAP];
    __shared__ float    s_wsum[NWAVES];
    __shared__ unsigned s_cnt;
    __shared__ int      s_r;
    __shared__ unsigned s_prefix;
    __shared__ int      s_shift;
    __shared__ unsigned s_thr;
    __shared__ int      s_e;
    __shared__ int      s_idxcut;
    __shared__ double   s_dS;
    __shared__ float    s_m;
    __shared__ unsigned s_b1;
    __shared__ int      s_minidx;

    const int t = threadIdx.x;
    const float* __restrict__ xrow = scores + (size_t)blockIdx.x * V_DIM;
    float* __restrict__ orow = out + (size_t)blockIdx.x * V_DIM;
    const float4* __restrict__ x4 = (const float4*)xrow;
    const int NV4 = V_DIM / 4;

    // ---------------- Pass A: 11-bit histogram of sortable keys ----------------
    for (int i = t; i < NBINS; i += BLOCK) hist[i] = 0;
    __syncthreads();
    for (int j = t; j < NV4; j += BLOCK) {
        float4 v = x4[j];
        atomicAdd(&hist[key_of(v.x) >> 21], 1u);
        atomicAdd(&hist[key_of(v.y) >> 21], 1u);
        atomicAdd(&hist[key_of(v.z) >> 21], 1u);
        atomicAdd(&hist[key_of(v.w) >> 21], 1u);
    }
    __syncthreads();
    chunk[t] = hist[2 * t] + hist[2 * t + 1];
    __syncthreads();
    if (t < 64) {
        unsigned s = 0;
        #pragma unroll
        for (int c = 0; c < 16; ++c) s += chunk[t * 16 + c];
        super_[t] = s;
    }
    __syncthreads();
    if (t == 0) {
        // descending scan: find bin b1 where cumulative count crosses K
        unsigned cum = 0; int b1 = -1;
        for (int s = 63; s >= 0 && b1 < 0; --s) {
            if (cum + super_[s] >= (unsigned)K_TOP) {
                for (int c = 16 * s + 15; c >= 16 * s && b1 < 0; --c) {
                    if (cum + chunk[c] >= (unsigned)K_TOP) {
                        for (int b = 2 * c + 1; b >= 2 * c && b1 < 0; --b) {
                            if (cum + hist[b] >= (unsigned)K_TOP) b1 = b;
                            else cum += hist[b];
                        }
                    } else cum += chunk[c];
                }
            } else cum += super_[s];
        }
        s_b1 = (unsigned)b1;
        s_r = K_TOP - (int)cum;          // rank within bin b1 (1-based)
        s_prefix = (unsigned)b1;
        s_shift = 21;
        s_m = val_of(((unsigned)b1 << 21) | 0x1FFFFFu);  // largest float in bin b1
        s_dS = 0.0;
    }
    __syncthreads();
    const float m = s_m;
    const unsigned b1 = s_b1;

    // ---------------- Pass B: collect candidates + sum exp below bin ----------------
    unsigned cnt;
    int iter = 0;
    for (;;) {
        if (t == 0) s_cnt = 0;
        for (int i = t; i < NBINS; i += BLOCK) { hist[i] = 0; hsum[i] = 0.f; }
        __syncthreads();
        const int shift = s_shift;
        const unsigned prefix = s_prefix;
        const int new_shift = (shift == 21) ? 10 : 0;
        const int nbits = shift - new_shift;
        const unsigned submask = (1u << nbits) - 1u;
        float lsum = 0.f;
        for (int j = t; j < NV4; j += BLOCK) {
            float4 v = x4[j];
            #pragma unroll
            for (int q = 0; q < 4; ++q) {
                float x = (q == 0) ? v.x : (q == 1) ? v.y : (q == 2) ? v.z : v.w;
                unsigned u = key_of(x);
                if ((u >> shift) == prefix) {
                    unsigned pos = atomicAdd(&s_cnt, 1u);
                    if (pos < CAP) { cand_u[pos] = u; cand_i[pos] = 4 * j + q; }
                    if (shift > 0) {   // sub-histogram for (unlikely) refinement
                        unsigned sb = (u >> new_shift) & submask;
                        atomicAdd(&hist[sb], 1u);
                        atomicAdd(&hsum[sb], __expf(x - m));
                    }
                } else if (iter == 0 && (u >> 21) < b1) {
                    lsum += __expf(x - m);   // definitely unmasked
                }
            }
        }
        // deterministic fixed-order reduce of lsum
        float ws = lsum;
        #pragma unroll
        for (int off = 32; off > 0; off >>= 1) ws += __shfl_down(ws, off);
        if ((t & 63) == 0) s_wsum[t >> 6] = ws;
        __syncthreads();
        if (t == 0 && iter == 0) {
            double d = 0.0;
            for (int w = 0; w < NWAVES; ++w) d += (double)s_wsum[w];
            s_dS += d;
        }
        __syncthreads();
        cnt = s_cnt;
        if (cnt <= CAP) break;      // normal path (expected ~140 candidates)
        if (shift == 0) break;      // pathological: >CAP exactly-equal values
        if (t == 0) {               // refine radix level
            int r = s_r; unsigned cum = 0; int sel = 0;
            for (int sb = (int)submask; sb >= 0; --sb) {
                if (cum + hist[sb] >= (unsigned)r) { sel = sb; break; }
                cum += hist[sb];
            }
            s_r = r - (int)cum;
            s_prefix = (prefix << nbits) | (unsigned)sel;
            s_shift = new_shift;
            double add = 0.0;       // matched elements below selected sub-bin: unmasked
            for (int sb = 0; sb < sel; ++sb) add += (double)hsum[sb];
            s_dS += add;
        }
        __syncthreads();
        ++iter;
    }
    __syncthreads();

    if (cnt <= CAP) {
        // exact selection among candidates: r-th largest with multiplicity
        const int r = s_r;
        const int c = (int)cnt;
        for (int j = t; j < c; j += BLOCK) {
            unsigned uj = cand_u[j];
            int g = 0, eq = 0;
            for (int k = 0; k < c; ++k) {
                unsigned uk = cand_u[k];
                g += (uk > uj) ? 1 : 0;
                eq += (uk == uj) ? 1 : 0;
            }
            if (g < r && r <= g + eq) { s_thr = uj; s_e = r - g; }
        }
        __syncthreads();
        const unsigned thr = s_thr; const int e = s_e;
        // e-th smallest index among ties (jax top_k masks lowest indices first)
        for (int j = t; j < c; j += BLOCK) {
            if (cand_u[j] == thr) {
                int ij = cand_i[j];
                int rank = 0;
                for (int k = 0; k < c; ++k)
                    rank += (cand_u[k] == thr && cand_i[k] < ij) ? 1 : 0;
                if (rank == e - 1) s_idxcut = ij;
            }
        }
        __syncthreads();
        if (t == 0) {
            double add = 0.0;
            const int idxcut = s_idxcut;
            for (int k = 0; k < c; ++k) {
                unsigned uk = cand_u[k];
                if (uk < thr || (uk == thr && cand_i[k] > idxcut))
                    add += (double)__expf(val_of(uk) - m);
            }
            s_dS += add;
        }
        __syncthreads();
    } else {
        // pathological: all matched equal value (full 32-bit prefix), count > CAP
        const unsigned thr = s_prefix;
        const int e = s_r;
        if (t == 0) {
            s_thr = thr;
            s_dS += (double)(cnt - (unsigned)e) * (double)__expf(val_of(thr) - m);
        }
        int last = -1;
        for (int it2 = 0; it2 < e; ++it2) {   // e<=50 min-index scans
            if (t == 0) s_minidx = 0x7FFFFFFF;
            __syncthreads();
            for (int j = t; j < NV4; j += BLOCK) {
                float4 v = x4[j];
                #pragma unroll
                for (int q = 0; q < 4; ++q) {
                    float x = (q == 0) ? v.x : (q == 1) ? v.y : (q == 2) ? v.z : v.w;
                    int idx = 4 * j + q;
                    if (key_of(x) == thr && idx > last) atomicMin(&s_minidx, idx);
                }
            }
            __syncthreads();
            last = s_minidx;
            __syncthreads();
        }
        if (t == 0) s_idxcut = last;
        __syncthreads();
    }

    // ---------------- Pass C: write softmax of masked row ----------------
    const unsigned thr = s_thr;
    const int idxcut = s_idxcut;
    const float invS = (float)(1.0 / s_dS);
    float4* __restrict__ o4 = (float4*)orow;
    for (int j = t; j < NV4; j += BLOCK) {
        float4 v = x4[j];
        float4 o;
        {
            unsigned u = key_of(v.x); int i = 4 * j;
            o.x = (u > thr || (u == thr && i <= idxcut)) ? 0.f : __expf(v.x - m) * invS;
        }
        {
            unsigned u = key_of(v.y); int i = 4 * j + 1;
            o.y = (u > thr || (u == thr && i <= idxcut)) ? 0.f : __expf(v.y - m) * invS;
        }
        {
            unsigned u = key_of(v.z); int i = 4 * j + 2;
            o.z = (u > thr || (u == thr && i <= idxcut)) ? 0.f : __expf(v.z - m) * invS;
        }
        {
            unsigned u = key_of(v.w); int i = 4 * j + 3;
            o.w = (u > thr || (u == thr && i <= idxcut)) ? 0.f : __expf(v.w - m) * invS;
        }
        o4[j] = o;
    }
}

extern "C" void kernel_launch(void* const* d_in, const int* in_sizes, int n_in,
                              void* d_out, int out_size, void* d_ws, size_t ws_size,
                              hipStream_t stream) {
    const float* scores = (const float*)d_in[0];
    float* out = (float*)d_out;
    const int B = in_sizes[0] / V_DIM;
    hipLaunchKernelGGL(topk_mask_softmax, dim3(B), dim3(BLOCK), 0, stream,
                       scores, out);
}